// Round 1
// baseline (508.018 us; speedup 1.0000x reference)
//
#include <hip/hip_runtime.h>
#include <hip/hip_bf16.h>

#define N_ROWS 32768
#define M_ROWS 8192
#define D_DIM  384
#define K_NB   9
#define BM     64
#define BN     64
#define N_TILES (M_ROWS / BN)   // 128
#define KSTEPS  (D_DIM / 32)    // 12

typedef __attribute__((ext_vector_type(8))) short short8;
typedef __attribute__((ext_vector_type(4))) float f32x4;

// ---------------- prep: f32 -> bf16 copies + f32 row norms ----------------
__global__ __launch_bounds__(256) void FAPM_prep(
    const float* __restrict__ emb, const float* __restrict__ mem,
    __hip_bfloat16* __restrict__ Ab, __hip_bfloat16* __restrict__ Bb,
    float* __restrict__ xn, float* __restrict__ yn) {
  const int lane = threadIdx.x & 63;
  const int row  = blockIdx.x * 4 + (threadIdx.x >> 6);
  const float* src;
  __hip_bfloat16* dst;
  float* nptr;
  if (row < N_ROWS) {
    src = emb + (size_t)row * D_DIM; dst = Ab + (size_t)row * D_DIM; nptr = xn + row;
  } else {
    int r = row - N_ROWS;
    src = mem + (size_t)r * D_DIM; dst = Bb + (size_t)r * D_DIM; nptr = yn + r;
  }
  float s = 0.f;
#pragma unroll
  for (int j = 0; j < 6; ++j) {
    float v = src[j * 64 + lane];
    s += v * v;
    dst[j * 64 + lane] = __float2bfloat16(v);
  }
#pragma unroll
  for (int dd = 1; dd < 64; dd <<= 1) s += __shfl_xor(s, dd);
  if (lane == 0) *nptr = s;
}

// ---------------- fused: bf16 MFMA distances + per-row top-9 ----------------
__global__ __launch_bounds__(256, 2) void FAPM_fused(
    const __hip_bfloat16* __restrict__ Ab, const __hip_bfloat16* __restrict__ Bb,
    const float* __restrict__ xn, const float* __restrict__ yn,
    float* __restrict__ out) {
  // B tile: 64 rows x 384 k, bf16, XOR-swizzled in 16B chunks (j ^= row&7)
  __shared__ __attribute__((aligned(128))) unsigned char Bs[BN * D_DIM * 2];  // 48 KB
  const int tid  = threadIdx.x;
  const int lane = tid & 63;
  const int w    = tid >> 6;     // wave 0..3, owns rows w*16..w*16+15
  const int sub  = lane & 15;
  const int grp  = lane >> 4;
  const int wrow0 = blockIdx.x * BM + w * 16;

  // A fragments in registers: lane holds A[wrow0+sub][grp*8 + 32*kk .. +8]
  short8 afrag[KSTEPS];
  {
    const __hip_bfloat16* ap = Ab + (size_t)(wrow0 + sub) * D_DIM + grp * 8;
#pragma unroll
    for (int kk = 0; kk < KSTEPS; ++kk)
      afrag[kk] = *(const short8*)(ap + kk * 32);
  }
  // x-norms for this lane's 4 output rows (C/D layout: row = grp*4 + i)
  float xr[4];
#pragma unroll
  for (int i = 0; i < 4; ++i) xr[i] = xn[wrow0 + grp * 4 + i];

  const float INF = 3.0e38f;
  float tk[4][9];  // per-lane running top-9 (ascending) for 4 rows
#pragma unroll
  for (int i = 0; i < 4; ++i)
#pragma unroll
    for (int j = 0; j < 9; ++j) tk[i][j] = INF;

  for (int t = 0; t < N_TILES; ++t) {
    const int col0 = t * BN;
    // ---- stage B tile: global_load_lds, linear LDS dest + swizzled global src ----
#pragma unroll
    for (int it = 0; it < 12; ++it) {
      int c   = (w * 12 + it) * 64 + lane;   // 16B-chunk index, 0..3071
      int row = c / 48;                      // 48 chunks per 768B row
      int jd  = c - row * 48;
      int js  = (jd & ~7) | ((jd ^ row) & 7);  // involution within 8-chunk group
      const void* src = (const void*)(Bb + (size_t)(col0 + row) * D_DIM + js * 8);
      void* ldst = (void*)(Bs + (size_t)(w * 12 + it) * 1024);  // wave-uniform base
      __builtin_amdgcn_global_load_lds(
          (const __attribute__((address_space(1))) void*)src,
          (__attribute__((address_space(3))) void*)ldst, 16, 0, 0);
    }
    asm volatile("s_waitcnt vmcnt(0)" ::: "memory");
    __syncthreads();

    // ---- GEMM + distance + top-9 update, 4 col-blocks of 16 ----
#pragma unroll
    for (int cb = 0; cb < 4; ++cb) {
      f32x4 acc = {0.f, 0.f, 0.f, 0.f};
      const int brow = cb * 16 + sub;  // B-tile row this lane reads (= its C col)
#pragma unroll
      for (int kk = 0; kk < KSTEPS; ++kk) {
        int jraw = kk * 4 + grp;
        int js   = (jraw & ~7) | ((jraw ^ sub) & 7);  // row&7 == sub&7
        short8 bfrag = *(const short8*)(Bs + brow * 768 + js * 16);
        acc = __builtin_amdgcn_mfma_f32_16x16x32_bf16(afrag[kk], bfrag, acc, 0, 0, 0);
      }
      float ync = yn[col0 + cb * 16 + sub];
#pragma unroll
      for (int i = 0; i < 4; ++i) {
        float d2 = fmaf(-2.f, acc[i], xr[i] + ync);
        float d  = sqrtf(fmaxf(d2, 0.f));
        // branchless sorted insert (ascending): t[j] = min(t[j], max(d, t[j-1]))
#pragma unroll
        for (int j = 8; j >= 1; --j)
          tk[i][j] = fminf(tk[i][j], fmaxf(d, tk[i][j - 1]));
        tk[i][0] = fminf(tk[i][0], d);
      }
    }
    __syncthreads();  // all reads of Bs done before next tile's staging
  }

  // ---- merge 16 per-lane sorted lists per row; extract 9 mins ascending ----
#pragma unroll
  for (int i = 0; i < 4; ++i) {
    size_t grow = (size_t)(wrow0 + grp * 4 + i);
    for (int s = 0; s < K_NB; ++s) {
      float m  = tk[i][0];
      int   ml = sub;
#pragma unroll
      for (int dd = 1; dd < 16; dd <<= 1) {
        float ov = __shfl_xor(m, dd);
        int   ol = __shfl_xor(ml, dd);
        bool take = (ov < m) || (ov == m && ol < ml);
        m  = take ? ov : m;
        ml = take ? ol : ml;
      }
      if (sub == ml) {  // owner pops its head
#pragma unroll
        for (int j = 0; j < 8; ++j) tk[i][j] = tk[i][j + 1];
        tk[i][8] = INF;
      }
      if (sub == 0) out[grow * 9 + s] = m;
    }
  }
}

extern "C" void kernel_launch(void* const* d_in, const int* in_sizes, int n_in,
                              void* d_out, int out_size, void* d_ws, size_t ws_size,
                              hipStream_t stream) {
  const float* emb = (const float*)d_in[0];
  const float* mem = (const float*)d_in[1];
  float* out = (float*)d_out;
  char* ws = (char*)d_ws;
  size_t offA = 0;
  size_t offB = offA + (size_t)N_ROWS * D_DIM * 2;   // 25,165,824
  size_t offX = offB + (size_t)M_ROWS * D_DIM * 2;   // +6,291,456
  size_t offY = offX + (size_t)N_ROWS * 4;           // +131,072  (total ~31.6 MB)
  __hip_bfloat16* Ab = (__hip_bfloat16*)(ws + offA);
  __hip_bfloat16* Bb = (__hip_bfloat16*)(ws + offB);
  float* xn = (float*)(ws + offX);
  float* yn = (float*)(ws + offY);

  FAPM_prep<<<(N_ROWS + M_ROWS) / 4, 256, 0, stream>>>(emb, mem, Ab, Bb, xn, yn);
  FAPM_fused<<<N_ROWS / BM, 256, 0, stream>>>(Ab, Bb, xn, yn, out);
}

// Round 2
// 249.901 us; speedup vs baseline: 2.0329x; 2.0329x over previous
//
#include <hip/hip_runtime.h>
#include <hip/hip_bf16.h>

#define N_ROWS 32768
#define M_ROWS 8192
#define D_DIM  384
#define K_NB   9
#define BN     64
#define MHALF  (M_ROWS / 2)      // 4096 per block
#define TILES  (MHALF / BN)      // 64
#define KSTEPS (D_DIM / 32)      // 12

typedef __attribute__((ext_vector_type(8))) short short8;
typedef __attribute__((ext_vector_type(4))) float f32x4;

#define BIG 3.0e38f

// ---------------- prep: f32 -> bf16 copies + f32 row norms ----------------
__global__ __launch_bounds__(256) void FAPM_prep(
    const float* __restrict__ emb, const float* __restrict__ mem,
    __hip_bfloat16* __restrict__ Ab, __hip_bfloat16* __restrict__ Bb,
    float* __restrict__ xn, float* __restrict__ yn) {
  const int lane = threadIdx.x & 63;
  const int row  = blockIdx.x * 4 + (threadIdx.x >> 6);
  const float* src;
  __hip_bfloat16* dst;
  float* nptr;
  if (row < N_ROWS) {
    src = emb + (size_t)row * D_DIM; dst = Ab + (size_t)row * D_DIM; nptr = xn + row;
  } else {
    int r = row - N_ROWS;
    src = mem + (size_t)r * D_DIM; dst = Bb + (size_t)r * D_DIM; nptr = yn + r;
  }
  float s = 0.f;
#pragma unroll
  for (int j = 0; j < 6; ++j) {
    float v = src[j * 64 + lane];
    s += v * v;
    dst[j * 64 + lane] = __float2bfloat16(v);
  }
#pragma unroll
  for (int dd = 1; dd < 64; dd <<= 1) s += __shfl_xor(s, dd);
  if (lane == 0) *nptr = s;
}

// ---- 16-lane merge of per-lane sorted top-9 lists; writes d^2 ascending ----
__device__ __forceinline__ void merge16(float t[9], float* dst, int sub) {
  for (int s = 0; s < K_NB; ++s) {
    float m  = t[0];
    int   ml = sub;
#pragma unroll
    for (int dd = 1; dd < 16; dd <<= 1) {
      float ov = __shfl_xor(m, dd);
      int   ol = __shfl_xor(ml, dd);
      bool take = (ov < m) || (ov == m && ol < ml);
      m  = take ? ov : m;
      ml = take ? ol : ml;
    }
    if (sub == ml) {  // owner pops its head
#pragma unroll
      for (int j = 0; j < 8; ++j) t[j] = t[j + 1];
      t[8] = BIG;
    }
    if (sub == 0) dst[s] = m;
  }
}

// ------- fused: bf16 MFMA d^2 + per-row top-9 (d^2 domain), half of M -------
__global__ __launch_bounds__(256, 2) void FAPM_fused(
    const __hip_bfloat16* __restrict__ Ab, const __hip_bfloat16* __restrict__ Bb,
    const float* __restrict__ xn, const float* __restrict__ yn,
    float* __restrict__ part) {
  // B tile 64x384 bf16 stored as 48 contiguous 1KB subtiles: [cb*12+kk][sub16][grp4]
  __shared__ __attribute__((aligned(128))) unsigned char Bs[48 * 1024];
  const int tid  = threadIdx.x;
  const int lane = tid & 63;
  const int w    = tid >> 6;         // wave 0..3
  const int sub  = lane & 15;
  const int grp  = lane >> 4;
  const int bx   = blockIdx.x;
  const int mh   = bx & 1;           // which M-half
  const int wrow0 = (bx >> 1) * 128 + w * 32;  // wave owns 32 rows
  const int colbase = mh * MHALF;

  // A fragments in registers: 2 row-blocks of 16
  short8 af0[KSTEPS], af1[KSTEPS];
  {
    const __hip_bfloat16* ap0 = Ab + (size_t)(wrow0 + sub) * D_DIM + grp * 8;
    const __hip_bfloat16* ap1 = ap0 + 16 * D_DIM;
#pragma unroll
    for (int kk = 0; kk < KSTEPS; ++kk) {
      af0[kk] = *(const short8*)(ap0 + kk * 32);
      af1[kk] = *(const short8*)(ap1 + kk * 32);
    }
  }
  float xr0[4], xr1[4];
#pragma unroll
  for (int i = 0; i < 4; ++i) {
    xr0[i] = xn[wrow0 + grp * 4 + i];
    xr1[i] = xn[wrow0 + 16 + grp * 4 + i];
  }

  float tk0[4][9], tk1[4][9];  // running top-9 in d^2, ascending
#pragma unroll
  for (int i = 0; i < 4; ++i)
#pragma unroll
    for (int j = 0; j < 9; ++j) { tk0[i][j] = BIG; tk1[i][j] = BIG; }

  const int s_row = lane >> 2;        // staging: row within 16
  const int s_kof = (lane & 3) * 8;   // staging: k offset (8 bf16 = 16B)
  const unsigned char* bread = Bs + sub * 64 + grp * 16;

  for (int t = 0; t < TILES; ++t) {
    const int col0 = colbase + t * BN;
    // ---- stage: wave w fills subtiles (w*12+q); linear LDS dest,
    //      per-lane global src delivers chunk (sub16*4+grp4) layout ----
    const __hip_bfloat16* bsrc =
        Bb + (size_t)(col0 + w * 16 + s_row) * D_DIM + s_kof;
#pragma unroll
    for (int q = 0; q < KSTEPS; ++q) {
      __builtin_amdgcn_global_load_lds(
          (const __attribute__((address_space(1))) void*)(bsrc + q * 32),
          (__attribute__((address_space(3))) void*)(Bs + (w * KSTEPS + q) * 1024),
          16, 0, 0);
    }
    float yv[4];
#pragma unroll
    for (int cb = 0; cb < 4; ++cb) yv[cb] = yn[col0 + cb * 16 + sub];
    asm volatile("s_waitcnt vmcnt(0)" ::: "memory");
    __syncthreads();

#pragma unroll
    for (int cb = 0; cb < 4; ++cb) {
      f32x4 acc0 = {0.f, 0.f, 0.f, 0.f}, acc1 = {0.f, 0.f, 0.f, 0.f};
#pragma unroll
      for (int kk = 0; kk < KSTEPS; ++kk) {
        short8 bf = *(const short8*)(bread + (cb * KSTEPS + kk) * 1024);
        acc0 = __builtin_amdgcn_mfma_f32_16x16x32_bf16(af0[kk], bf, acc0, 0, 0, 0);
        acc1 = __builtin_amdgcn_mfma_f32_16x16x32_bf16(af1[kk], bf, acc1, 0, 0, 0);
      }
#pragma unroll
      for (int i = 0; i < 4; ++i) {
        float d2a = fmaf(-2.f, acc0[i], xr0[i] + yv[cb]);
#pragma unroll
        for (int j = 8; j >= 1; --j)
          tk0[i][j] = __builtin_amdgcn_fmed3f(d2a, tk0[i][j - 1], tk0[i][j]);
        tk0[i][0] = fminf(tk0[i][0], d2a);
        float d2b = fmaf(-2.f, acc1[i], xr1[i] + yv[cb]);
#pragma unroll
        for (int j = 8; j >= 1; --j)
          tk1[i][j] = __builtin_amdgcn_fmed3f(d2b, tk1[i][j - 1], tk1[i][j]);
        tk1[i][0] = fminf(tk1[i][0], d2b);
      }
    }
    __syncthreads();
  }

  // ---- per-row merge across 16 sub-lanes; write d^2 partials ----
  float* pbase = part + (size_t)mh * N_ROWS * K_NB;
#pragma unroll
  for (int i = 0; i < 4; ++i) {
    merge16(tk0[i], pbase + (size_t)(wrow0 + grp * 4 + i) * K_NB, sub);
    merge16(tk1[i], pbase + (size_t)(wrow0 + 16 + grp * 4 + i) * K_NB, sub);
  }
}

// ------- merge the two M-half partials, clamp+sqrt, final output -------
__global__ __launch_bounds__(256) void FAPM_merge(
    const float* __restrict__ part, float* __restrict__ out) {
  const int r = blockIdx.x * 256 + threadIdx.x;
  const float* pa = part + (size_t)r * K_NB;
  const float* pb = part + (size_t)N_ROWS * K_NB + (size_t)r * K_NB;
  float a[9], b[9];
#pragma unroll
  for (int j = 0; j < 9; ++j) { a[j] = pa[j]; b[j] = pb[j]; }
#pragma unroll
  for (int s = 0; s < K_NB; ++s) {
    bool ta = a[0] <= b[0];
    float m = ta ? a[0] : b[0];
    out[(size_t)r * K_NB + s] = sqrtf(fmaxf(m, 0.f));
    // predicated shift of the taken list (static indexing only)
#pragma unroll
    for (int j = 0; j < 8; ++j) {
      float an = a[j + 1], bn = b[j + 1];
      a[j] = ta ? an : a[j];
      b[j] = ta ? b[j] : bn;
    }
    a[8] = ta ? BIG : a[8];
    b[8] = ta ? b[8] : BIG;
  }
}

extern "C" void kernel_launch(void* const* d_in, const int* in_sizes, int n_in,
                              void* d_out, int out_size, void* d_ws, size_t ws_size,
                              hipStream_t stream) {
  const float* emb = (const float*)d_in[0];
  const float* mem = (const float*)d_in[1];
  float* out = (float*)d_out;
  char* ws = (char*)d_ws;
  size_t offA = 0;
  size_t offB = offA + (size_t)N_ROWS * D_DIM * 2;   // A bf16: 25,165,824
  size_t offX = offB + (size_t)M_ROWS * D_DIM * 2;   // B bf16: +6,291,456
  size_t offY = offX + (size_t)N_ROWS * 4;           // +131,072
  size_t offP = offY + (size_t)M_ROWS * 4;           // +32,768
  // partials: 2 halves x N x 9 f32 = 2,359,296  (total ~34 MB)
  __hip_bfloat16* Ab = (__hip_bfloat16*)(ws + offA);
  __hip_bfloat16* Bb = (__hip_bfloat16*)(ws + offB);
  float* xn = (float*)(ws + offX);
  float* yn = (float*)(ws + offY);
  float* part = (float*)(ws + offP);

  FAPM_prep<<<(N_ROWS + M_ROWS) / 4, 256, 0, stream>>>(emb, mem, Ab, Bb, xn, yn);
  FAPM_fused<<<(N_ROWS / 128) * 2, 256, 0, stream>>>(Ab, Bb, xn, yn, part);
  FAPM_merge<<<N_ROWS / 256, 256, 0, stream>>>(part, out);
}